// Round 12
// baseline (129.743 us; speedup 1.0000x reference)
//
#include <hip/hip_runtime.h>

#define HW 512
#define NSTATE (HW * HW)   // 262144
#define NC4_X 196608       // x as float4 (3*H*W/4)
#define NC4_POLROW 262144  // Wpol row stride in float4 (4 MiB — power of 2!)
#define NC4_V 65536        // v as float4

#define CH4 1024   // float4 per wave-chunk (16 KB)
#define NCH_X 192  // chunks per W1 row / per WpolX row
#define NCH_V 64   // chunks per WpolV row
#define SPAN_ROP 1024

// ws layout (float offsets)
#define WS_PART1 0       // 192*32
#define WS_PARTPX 6144   // 192*32
#define WS_PARTPV 12288  // 64*32
#define WS_H2 14336      // 64
#define WS_P 14400       // 262144
#define WS_RD (WS_P + NSTATE)
#define WS_V (WS_RD + NSTATE)

#define SGB __builtin_amdgcn_sched_group_barrier

__device__ __forceinline__ float wred(float a) {
  a += __shfl_xor(a, 32);
  a += __shfl_xor(a, 16);
  a += __shfl_xor(a, 8);
  a += __shfl_xor(a, 4);
  a += __shfl_xor(a, 2);
  a += __shfl_xor(a, 1);
  return a;
}

// One wave: dot of a contiguous 16 KB W span with the matching x span, both
// straight from global as 16-load bursts (single base + immediate offsets).
__device__ __forceinline__ float span_dot(const float4* __restrict__ wp,
                                          const float4* __restrict__ xp) {
  float acc = 0.f;
#pragma unroll
  for (int bt = 0; bt < 2; ++bt) {
    float4 w[8], xv[8];
#pragma unroll
    for (int j = 0; j < 8; ++j) w[j] = wp[bt * 512 + j * 64];
#pragma unroll
    for (int j = 0; j < 8; ++j) xv[j] = xp[bt * 512 + j * 64];
    SGB(0x020, 16, 0);  // the 16-load cluster
#pragma unroll
    for (int j = 0; j < 8; ++j)
      acc += w[j].x * xv[j].x + w[j].y * xv[j].y + w[j].z * xv[j].z +
             w[j].w * xv[j].w;
  }
  return acc;
}

// ---------------------------------------------------------------------------
// K1: W1@x AND Wpol[:, x-cols]@x partials, one homogeneous launch.
// Blocks [0,1536): W1 flat-linear (proven fast; 3 MiB row stride
// decorrelates the 32 concurrent row-streams in L2-set space).
// Blocks [1536,3072): WpolX — row stride is 4 MiB = L2-size power-of-2, so
// the 32 streams alias the SAME L2 sets at equal progress (R3-R11: every
// Wpol-x kernel pinned at ~1.5-2 TB/s regardless of micro-structure).
// Fix: per-row chunk-order ROTATION ch=(c0+row*29)%192 (29 coprime 192) —
// same addresses, same coalescing, but concurrent streams sit at distinct
// ~464 KB phases -> distinct L2 sets.
// ---------------------------------------------------------------------------
__global__ __launch_bounds__(256) void mv_x(const float4* __restrict__ W1,
                                            const float4* __restrict__ Wpol,
                                            const float4* __restrict__ x,
                                            float* __restrict__ part1,
                                            float* __restrict__ partPx) {
  int b = blockIdx.x;  // [0,3072)
  int tid = threadIdx.x, wave = tid >> 6, lane = tid & 63;
  const float4* __restrict__ wp;
  const float4* __restrict__ xp;
  float* outp;
  int row, ch;
  if (b < 1536) {  // W1, identity order
    row = b / 48;
    ch = (b - row * 48) * 4 + wave;  // 0..191
    wp = W1 + (size_t)row * NC4_X + (size_t)ch * CH4 + lane;
    outp = part1;
  } else {  // WpolX, rotated order
    int bb = b - 1536;
    row = bb / 48;
    int c0 = (bb - row * 48) * 4 + wave;
    ch = (c0 + row * 29) % NCH_X;
    wp = Wpol + (size_t)row * NC4_POLROW + NC4_V + (size_t)ch * CH4 + lane;
    outp = partPx;
  }
  xp = x + (size_t)ch * CH4 + lane;
  float acc = span_dot(wp, xp);
  acc = wred(acc);
  if (lane == 0) outp[ch * 32 + row] = acc;
}

// ---------------------------------------------------------------------------
// finish_h: reduce part1[192][32] -> h1 = relu(W1@x+b1); h2 = relu(W2@h1+b2).
// ---------------------------------------------------------------------------
__global__ __launch_bounds__(1024) void finish_h(
    const float* __restrict__ partials, const float* __restrict__ b1,
    const float* __restrict__ W2, const float* __restrict__ b2,
    float* __restrict__ h2out) {
  __shared__ float red[32][32];
  __shared__ float h1[32];
  int tid = threadIdx.x;
  int row = tid & 31, grp = tid >> 5;
  float s = 0.f;
  for (int b = grp; b < NCH_X; b += 32) s += partials[b * 32 + row];
  red[grp][row] = s;
  __syncthreads();
  if (tid < 32) {
    float t = b1[tid];
    for (int g = 0; g < 32; ++g) t += red[g][tid];
    h1[tid] = fmaxf(t, 0.f);
  }
  __syncthreads();
  if (tid < 64) {
    float t = b2[tid];
    for (int k = 0; k < 32; ++k) t += W2[tid * 32 + k] * h1[k];
    h2out[tid] = fmaxf(t, 0.f);
  }
}

// ---------------------------------------------------------------------------
// rop: p = sig(Wp@h2+bp), rd = sig(Wri@h2+bri) - sig(Wro@h2+bro).
// R5's standalone measured-fast form, unchanged. 1024 blocks.
// ---------------------------------------------------------------------------
__global__ __launch_bounds__(256) void rop_kernel(
    const float4* __restrict__ Wro4, const float* __restrict__ bro,
    const float4* __restrict__ Wri4, const float* __restrict__ bri,
    const float4* __restrict__ Wp4, const float* __restrict__ bp,
    const float* __restrict__ h2, float* __restrict__ p_out,
    float* __restrict__ rd_out) {
  __shared__ float dots[4][3][64];
  int tid = threadIdx.x;
  int wave = tid >> 6, lane = tid & 63;
  int grp = lane >> 4;
  float4 h4 = ((const float4*)h2)[lane & 15];
  int span = blockIdx.x * 4 + wave;       // [0,4096)
  size_t base = (size_t)span * SPAN_ROP;  // first float4 of span
  const float4* mats[3] = {Wro4, Wri4, Wp4};
#pragma unroll
  for (int m = 0; m < 3; ++m) {
    const float4* __restrict__ W = mats[m] + base + lane;
#pragma unroll
    for (int batch = 0; batch < 2; ++batch) {
      float4 w[8];
#pragma unroll
      for (int j = 0; j < 8; ++j) w[j] = W[(batch * 8 + j) * 64];
      SGB(0x020, 8, 0);
      float part[8];
#pragma unroll
      for (int j = 0; j < 8; ++j)
        part[j] = w[j].x * h4.x + w[j].y * h4.y + w[j].z * h4.z + w[j].w * h4.w;
#pragma unroll
      for (int j = 0; j < 8; ++j) {
        part[j] += __shfl_xor(part[j], 8);
        part[j] += __shfl_xor(part[j], 4);
        part[j] += __shfl_xor(part[j], 2);
        part[j] += __shfl_xor(part[j], 1);
      }
      if ((lane & 15) == 0) {
#pragma unroll
        for (int j = 0; j < 8; ++j)
          dots[wave][m][(batch * 8 + j) * 4 + grp] = part[j];
      }
    }
  }
  __syncthreads();
  int o = blockIdx.x * 256 + tid;
  float dro = dots[tid >> 6][0][tid & 63] + bro[o];
  float dri = dots[tid >> 6][1][tid & 63] + bri[o];
  float dp = dots[tid >> 6][2][tid & 63] + bp[o];
  float sro = 1.f / (1.f + __expf(-dro));
  float sri = 1.f / (1.f + __expf(-dri));
  float pv = 1.f / (1.f + __expf(-dp));
  p_out[o] = pv;
  rd_out[o] = sri - sro;
}

// ---------------------------------------------------------------------------
// Value iteration, ONE launch, 1024 blocks. 16x16 tile + halo 10 in LDS,
// 10 local iterations; zero-padding semantics preserved.
// ---------------------------------------------------------------------------
#define TILE 16
#define HALO 10
#define LR 36  // TILE + 2*HALO
__global__ __launch_bounds__(256) void valiter_kernel(
    const float* __restrict__ p, const float* __restrict__ rd,
    float* __restrict__ vout) {
  __shared__ float u[LR + 2][LR + 3];
  __shared__ float pp[LR][LR + 1];
  __shared__ float rr[LR][LR + 1];
  __shared__ float vv[LR][LR + 1];
  int tid = threadIdx.x;
  int ti = blockIdx.x >> 5, tj = blockIdx.x & 31;
  int gi0 = ti * TILE - HALO, gj0 = tj * TILE - HALO;
  for (int idx = tid; idx < (LR + 2) * (LR + 3); idx += 256)
    ((float*)u)[idx] = 0.f;
  for (int idx = tid; idx < LR * LR; idx += 256) {
    int i = idx / LR, j = idx % LR;
    int gi = gi0 + i, gj = gj0 + j;
    bool ok = (gi >= 0) & (gi < HW) & (gj >= 0) & (gj < HW);
    pp[i][j] = ok ? p[gi * HW + gj] : 0.f;
    rr[i][j] = ok ? rd[gi * HW + gj] : 0.f;
    vv[i][j] = 0.f;
  }
  __syncthreads();
  for (int k = 0; k < 10; ++k) {
#pragma unroll
    for (int idx = tid; idx < LR * LR; idx += 256) {
      int i = idx / LR, j = idx % LR;
      u[i + 1][j + 1] = vv[i][j] * pp[i][j] + rr[i][j];
    }
    __syncthreads();
#pragma unroll
    for (int idx = tid; idx < LR * LR; idx += 256) {
      int i = idx / LR, j = idx % LR;
      float m = u[i][j];
      m = fmaxf(m, u[i][j + 1]);
      m = fmaxf(m, u[i][j + 2]);
      m = fmaxf(m, u[i + 1][j]);
      m = fmaxf(m, u[i + 1][j + 2]);
      m = fmaxf(m, u[i + 2][j]);
      m = fmaxf(m, u[i + 2][j + 1]);
      m = fmaxf(m, u[i + 2][j + 2]);
      vv[i][j] = m;
    }
    __syncthreads();
  }
  if (tid < TILE * TILE) {
    int a = tid >> 4, b = tid & 15;
    vout[(ti * TILE + a) * HW + tj * TILE + b] = vv[HALO + a][HALO + b];
  }
}

// ---------------------------------------------------------------------------
// K5: Wpol[:, v-cols] @ v partials, rotated order (same 4 MiB-stride fix:
// ch=(c0+row*13)%64, 13 coprime 64). 512 blocks.
// ---------------------------------------------------------------------------
__global__ __launch_bounds__(256) void mv_polv(const float4* __restrict__ Wpol,
                                               const float4* __restrict__ v,
                                               float* __restrict__ partPv) {
  int b = blockIdx.x;  // [0,512)
  int row = b / 16;
  int tid = threadIdx.x, wave = tid >> 6, lane = tid & 63;
  int c0 = (b - row * 16) * 4 + wave;
  int ch = (c0 + row * 13) % NCH_V;  // rotated chunk 0..63
  const float4* __restrict__ wp =
      Wpol + (size_t)row * NC4_POLROW + (size_t)ch * CH4 + lane;
  const float4* __restrict__ xp = v + (size_t)ch * CH4 + lane;
  float acc = span_dot(wp, xp);
  acc = wred(acc);
  if (lane == 0) partPv[ch * 32 + row] = acc;
}

// ---------------------------------------------------------------------------
// finish_pol: hp = relu(bpol + sum partPx[192][32] + sum partPv[64][32]);
// logits = Whead@hp + bhead; softmax; out[8] = v[pos].
// ---------------------------------------------------------------------------
__global__ __launch_bounds__(1024) void finish_pol(
    const float* __restrict__ partPx, const float* __restrict__ partPv,
    const float* __restrict__ bpol, const float* __restrict__ Whead,
    const float* __restrict__ bhead, const float* __restrict__ v,
    const int* __restrict__ pos, float* __restrict__ out) {
  __shared__ float red[32][32];
  __shared__ float hp[32];
  __shared__ float logits[8];
  int tid = threadIdx.x;
  int row = tid & 31, grp = tid >> 5;
  float s = 0.f;
  for (int b = grp; b < NCH_X; b += 32) s += partPx[b * 32 + row];
  for (int b = grp; b < NCH_V; b += 32) s += partPv[b * 32 + row];
  red[grp][row] = s;
  __syncthreads();
  if (tid < 32) {
    float t = bpol[tid];
    for (int g = 0; g < 32; ++g) t += red[g][tid];
    hp[tid] = fmaxf(t, 0.f);
  }
  __syncthreads();
  if (tid < 8) {
    float t = bhead[tid];
    for (int k = 0; k < 32; ++k) t += Whead[tid * 32 + k] * hp[k];
    logits[tid] = t;
  }
  __syncthreads();
  if (tid == 0) {
    float mx = logits[0];
    for (int j = 1; j < 8; ++j) mx = fmaxf(mx, logits[j]);
    float e[8], sum = 0.f;
    for (int j = 0; j < 8; ++j) {
      e[j] = __expf(logits[j] - mx);
      sum += e[j];
    }
    for (int j = 0; j < 8; ++j) out[j] = e[j] / sum;
    out[8] = v[pos[0] * HW + pos[1]];
  }
}

extern "C" void kernel_launch(void* const* d_in, const int* in_sizes, int n_in,
                              void* d_out, int out_size, void* d_ws,
                              size_t ws_size, hipStream_t stream) {
  const float* x = (const float*)d_in[0];
  const int* pos = (const int*)d_in[1];
  const float* W1 = (const float*)d_in[2];
  const float* b1 = (const float*)d_in[3];
  const float* W2 = (const float*)d_in[4];
  const float* b2 = (const float*)d_in[5];
  const float* Wro = (const float*)d_in[6];
  const float* bro = (const float*)d_in[7];
  const float* Wri = (const float*)d_in[8];
  const float* bri = (const float*)d_in[9];
  const float* Wp = (const float*)d_in[10];
  const float* bp = (const float*)d_in[11];
  const float* Wpol = (const float*)d_in[12];
  const float* bpol = (const float*)d_in[13];
  const float* Whead = (const float*)d_in[14];
  const float* bhead = (const float*)d_in[15];
  float* ws = (float*)d_ws;
  float* out = (float*)d_out;

  float* part1 = ws + WS_PART1;
  float* partPx = ws + WS_PARTPX;
  float* partPv = ws + WS_PARTPV;
  float* h2 = ws + WS_H2;
  float* pbuf = ws + WS_P;
  float* rdbuf = ws + WS_RD;
  float* vbuf = ws + WS_V;

  // K1: W1@x + WpolX partials (one homogeneous launch; polx rotated)
  mv_x<<<3072, 256, 0, stream>>>((const float4*)W1, (const float4*)Wpol,
                                 (const float4*)x, part1, partPx);
  // K2: h1 -> h2
  finish_h<<<1, 1024, 0, stream>>>(part1, b1, W2, b2, h2);
  // K3: p, rd
  rop_kernel<<<1024, 256, 0, stream>>>((const float4*)Wro, bro,
                                       (const float4*)Wri, bri,
                                       (const float4*)Wp, bp, h2, pbuf, rdbuf);
  // K4: 10 value-iteration steps, one launch
  valiter_kernel<<<1024, 256, 0, stream>>>(pbuf, rdbuf, vbuf);
  // K5: WpolV partials (rotated)
  mv_polv<<<512, 256, 0, stream>>>((const float4*)Wpol, (const float4*)vbuf,
                                   partPv);
  // K6: heads + softmax + state value
  finish_pol<<<1, 1024, 0, stream>>>(partPx, partPv, bpol, Whead, bhead, vbuf,
                                     pos, out);
}

// Round 13
// 127.771 us; speedup vs baseline: 1.0154x; 1.0154x over previous
//
#include <hip/hip_runtime.h>

#define HW 512
#define NSTATE (HW * HW)   // 262144
#define NC4_X 196608       // x as float4 (3*H*W/4)
#define NC4_POLROW 262144  // Wpol row stride in float4 (4 MiB)
#define NC4_V 65536        // v as float4

#define CH4 1024   // float4 per wave-chunk (16 KB)
#define NCH_X 192  // chunks per W1 row
#define NCH_V 64   // chunks per WpolV row
#define SPAN_ROP 1024

// ws layout (float offsets)
#define WS_PART1 0       // 192*32 = 6144
#define WS_PARTPX 6144   // 256*32 = 8192 (rows 0..63 are discard)
#define WS_PARTPV 14336  // 64*32 = 2048
#define WS_H2 16384      // 64
#define WS_P 16448       // 262144
#define WS_RD (WS_P + NSTATE)
#define WS_V (WS_RD + NSTATE)

#define SGB __builtin_amdgcn_sched_group_barrier

__device__ __forceinline__ float wred(float a) {
  a += __shfl_xor(a, 32);
  a += __shfl_xor(a, 16);
  a += __shfl_xor(a, 8);
  a += __shfl_xor(a, 4);
  a += __shfl_xor(a, 2);
  a += __shfl_xor(a, 1);
  return a;
}

// One wave: dot of a contiguous 16 KB W span with the matching x span, both
// straight from global as 16-load bursts (single base + immediate offsets).
__device__ __forceinline__ float span_dot(const float4* __restrict__ wp,
                                          const float4* __restrict__ xp) {
  float acc = 0.f;
#pragma unroll
  for (int bt = 0; bt < 2; ++bt) {
    float4 w[8], xv[8];
#pragma unroll
    for (int j = 0; j < 8; ++j) w[j] = wp[bt * 512 + j * 64];
#pragma unroll
    for (int j = 0; j < 8; ++j) xv[j] = xp[bt * 512 + j * 64];
    SGB(0x020, 16, 0);  // the 16-load cluster
#pragma unroll
    for (int j = 0; j < 8; ++j)
      acc += w[j].x * xv[j].x + w[j].y * xv[j].y + w[j].z * xv[j].z +
             w[j].w * xv[j].w;
  }
  return acc;
}

// ---------------------------------------------------------------------------
// K1: W1@x partials, flat-linear over the W1 allocation (confirmed at the
// 16 µs / 6.3 TB/s floor via R10/R11 budgets). 1536 blocks.
// ---------------------------------------------------------------------------
__global__ __launch_bounds__(256) void mv_w1(const float4* __restrict__ W1,
                                             const float4* __restrict__ x,
                                             float* __restrict__ part1) {
  int b = blockIdx.x;  // [0,1536)
  int row = b / 48, cb = b - row * 48;
  int tid = threadIdx.x, wave = tid >> 6, lane = tid & 63;
  int ch = cb * 4 + wave;  // chunk-in-row 0..191
  const float4* __restrict__ wp =
      W1 + (size_t)row * NC4_X + (size_t)ch * CH4 + lane;
  const float4* __restrict__ xp = x + (size_t)ch * CH4 + lane;
  float acc = span_dot(wp, xp);
  acc = wred(acc);
  if (lane == 0) part1[ch * 32 + row] = acc;
}

// ---------------------------------------------------------------------------
// K1b: Wpol x-column partials as a FLAT SWEEP OF THE WHOLE Wpol ALLOCATION.
// R3-R12: polx with per-row base arithmetic (+1 MiB offset, 4 MiB stride)
// pinned at ~1.6 TB/s across NINE structures; every measured-fast big read
// (mv_w1, rop) is a pure flat sweep of one allocation. One variable left:
// make polx flat. Flat chunk f = (row=f>>8, rc=f&255); v-column chunks
// (rc<64) are STILL LOADED (keeping the sweep hole-free) and dotted against
// a valid dummy x chunk, written to the discard rows (<64) of partPx.
// finish_pol sums only rc>=64 against x chunk rc-64. 2048 blocks, 128 MiB.
// ---------------------------------------------------------------------------
__global__ __launch_bounds__(256) void mv_polx(const float4* __restrict__ Wpol,
                                               const float4* __restrict__ x,
                                               float* __restrict__ partPx) {
  int b = blockIdx.x;  // [0,2048)
  int tid = threadIdx.x, wave = tid >> 6, lane = tid & 63;
  int f = b * 4 + wave;  // flat chunk [0,8192)
  int row = f >> 8, rc = f & 255;
  const float4* __restrict__ wp = Wpol + (size_t)f * CH4 + lane;  // flat!
  int xc = rc < 64 ? rc : rc - 64;
  const float4* __restrict__ xp = x + (size_t)xc * CH4 + lane;
  float acc = span_dot(wp, xp);
  acc = wred(acc);
  if (lane == 0) partPx[rc * 32 + row] = acc;
}

// ---------------------------------------------------------------------------
// finish_h: reduce part1[192][32] -> h1 = relu(W1@x+b1); h2 = relu(W2@h1+b2).
// ---------------------------------------------------------------------------
__global__ __launch_bounds__(1024) void finish_h(
    const float* __restrict__ partials, const float* __restrict__ b1,
    const float* __restrict__ W2, const float* __restrict__ b2,
    float* __restrict__ h2out) {
  __shared__ float red[32][32];
  __shared__ float h1[32];
  int tid = threadIdx.x;
  int row = tid & 31, grp = tid >> 5;
  float s = 0.f;
  for (int b = grp; b < NCH_X; b += 32) s += partials[b * 32 + row];
  red[grp][row] = s;
  __syncthreads();
  if (tid < 32) {
    float t = b1[tid];
    for (int g = 0; g < 32; ++g) t += red[g][tid];
    h1[tid] = fmaxf(t, 0.f);
  }
  __syncthreads();
  if (tid < 64) {
    float t = b2[tid];
    for (int k = 0; k < 32; ++k) t += W2[tid * 32 + k] * h1[k];
    h2out[tid] = fmaxf(t, 0.f);
  }
}

// ---------------------------------------------------------------------------
// rop: p = sig(Wp@h2+bp), rd = sig(Wri@h2+bri) - sig(Wro@h2+bro).
// R5's standalone measured-fast form, unchanged. 1024 blocks.
// ---------------------------------------------------------------------------
__global__ __launch_bounds__(256) void rop_kernel(
    const float4* __restrict__ Wro4, const float* __restrict__ bro,
    const float4* __restrict__ Wri4, const float* __restrict__ bri,
    const float4* __restrict__ Wp4, const float* __restrict__ bp,
    const float* __restrict__ h2, float* __restrict__ p_out,
    float* __restrict__ rd_out) {
  __shared__ float dots[4][3][64];
  int tid = threadIdx.x;
  int wave = tid >> 6, lane = tid & 63;
  int grp = lane >> 4;
  float4 h4 = ((const float4*)h2)[lane & 15];
  int span = blockIdx.x * 4 + wave;       // [0,4096)
  size_t base = (size_t)span * SPAN_ROP;  // first float4 of span
  const float4* mats[3] = {Wro4, Wri4, Wp4};
#pragma unroll
  for (int m = 0; m < 3; ++m) {
    const float4* __restrict__ W = mats[m] + base + lane;
#pragma unroll
    for (int batch = 0; batch < 2; ++batch) {
      float4 w[8];
#pragma unroll
      for (int j = 0; j < 8; ++j) w[j] = W[(batch * 8 + j) * 64];
      SGB(0x020, 8, 0);
      float part[8];
#pragma unroll
      for (int j = 0; j < 8; ++j)
        part[j] = w[j].x * h4.x + w[j].y * h4.y + w[j].z * h4.z + w[j].w * h4.w;
#pragma unroll
      for (int j = 0; j < 8; ++j) {
        part[j] += __shfl_xor(part[j], 8);
        part[j] += __shfl_xor(part[j], 4);
        part[j] += __shfl_xor(part[j], 2);
        part[j] += __shfl_xor(part[j], 1);
      }
      if ((lane & 15) == 0) {
#pragma unroll
        for (int j = 0; j < 8; ++j)
          dots[wave][m][(batch * 8 + j) * 4 + grp] = part[j];
      }
    }
  }
  __syncthreads();
  int o = blockIdx.x * 256 + tid;
  float dro = dots[tid >> 6][0][tid & 63] + bro[o];
  float dri = dots[tid >> 6][1][tid & 63] + bri[o];
  float dp = dots[tid >> 6][2][tid & 63] + bp[o];
  float sro = 1.f / (1.f + __expf(-dro));
  float sri = 1.f / (1.f + __expf(-dri));
  float pv = 1.f / (1.f + __expf(-dp));
  p_out[o] = pv;
  rd_out[o] = sri - sro;
}

// ---------------------------------------------------------------------------
// Value iteration, ONE launch, 1024 blocks. 16x16 tile + halo 10 in LDS,
// 10 local iterations; zero-padding semantics preserved.
// ---------------------------------------------------------------------------
#define TILE 16
#define HALO 10
#define LR 36  // TILE + 2*HALO
__global__ __launch_bounds__(256) void valiter_kernel(
    const float* __restrict__ p, const float* __restrict__ rd,
    float* __restrict__ vout) {
  __shared__ float u[LR + 2][LR + 3];
  __shared__ float pp[LR][LR + 1];
  __shared__ float rr[LR][LR + 1];
  __shared__ float vv[LR][LR + 1];
  int tid = threadIdx.x;
  int ti = blockIdx.x >> 5, tj = blockIdx.x & 31;
  int gi0 = ti * TILE - HALO, gj0 = tj * TILE - HALO;
  for (int idx = tid; idx < (LR + 2) * (LR + 3); idx += 256)
    ((float*)u)[idx] = 0.f;
  for (int idx = tid; idx < LR * LR; idx += 256) {
    int i = idx / LR, j = idx % LR;
    int gi = gi0 + i, gj = gj0 + j;
    bool ok = (gi >= 0) & (gi < HW) & (gj >= 0) & (gj < HW);
    pp[i][j] = ok ? p[gi * HW + gj] : 0.f;
    rr[i][j] = ok ? rd[gi * HW + gj] : 0.f;
    vv[i][j] = 0.f;
  }
  __syncthreads();
  for (int k = 0; k < 10; ++k) {
#pragma unroll
    for (int idx = tid; idx < LR * LR; idx += 256) {
      int i = idx / LR, j = idx % LR;
      u[i + 1][j + 1] = vv[i][j] * pp[i][j] + rr[i][j];
    }
    __syncthreads();
#pragma unroll
    for (int idx = tid; idx < LR * LR; idx += 256) {
      int i = idx / LR, j = idx % LR;
      float m = u[i][j];
      m = fmaxf(m, u[i][j + 1]);
      m = fmaxf(m, u[i][j + 2]);
      m = fmaxf(m, u[i + 1][j]);
      m = fmaxf(m, u[i + 1][j + 2]);
      m = fmaxf(m, u[i + 2][j]);
      m = fmaxf(m, u[i + 2][j + 1]);
      m = fmaxf(m, u[i + 2][j + 2]);
      vv[i][j] = m;
    }
    __syncthreads();
  }
  if (tid < TILE * TILE) {
    int a = tid >> 4, b = tid & 15;
    vout[(ti * TILE + a) * HW + tj * TILE + b] = vv[HALO + a][HALO + b];
  }
}

// ---------------------------------------------------------------------------
// K5: Wpol[:, v-cols] @ v partials, flat-linear (R11 form — budget-confirmed
// fast). 512 blocks.
// ---------------------------------------------------------------------------
__global__ __launch_bounds__(256) void mv_polv(const float4* __restrict__ Wpol,
                                               const float4* __restrict__ v,
                                               float* __restrict__ partPv) {
  int b = blockIdx.x;  // [0,512)
  int row = b / 16, cb = b - row * 16;
  int tid = threadIdx.x, wave = tid >> 6, lane = tid & 63;
  int ch = cb * 4 + wave;  // 0..63
  const float4* __restrict__ wp =
      Wpol + (size_t)row * NC4_POLROW + (size_t)ch * CH4 + lane;
  const float4* __restrict__ xp = v + (size_t)ch * CH4 + lane;
  float acc = span_dot(wp, xp);
  acc = wred(acc);
  if (lane == 0) partPv[ch * 32 + row] = acc;
}

// ---------------------------------------------------------------------------
// finish_pol: hp = relu(bpol + sum partPx[64..255][32] + sum partPv[64][32]);
// logits = Whead@hp + bhead; softmax; out[8] = v[pos]. partPx rows <64 are
// the flat-sweep discard region — skipped.
// ---------------------------------------------------------------------------
__global__ __launch_bounds__(1024) void finish_pol(
    const float* __restrict__ partPx, const float* __restrict__ partPv,
    const float* __restrict__ bpol, const float* __restrict__ Whead,
    const float* __restrict__ bhead, const float* __restrict__ v,
    const int* __restrict__ pos, float* __restrict__ out) {
  __shared__ float red[32][32];
  __shared__ float hp[32];
  __shared__ float logits[8];
  int tid = threadIdx.x;
  int row = tid & 31, grp = tid >> 5;
  float s = 0.f;
  for (int b = 64 + grp; b < 256; b += 32) s += partPx[b * 32 + row];
  for (int b = grp; b < NCH_V; b += 32) s += partPv[b * 32 + row];
  red[grp][row] = s;
  __syncthreads();
  if (tid < 32) {
    float t = bpol[tid];
    for (int g = 0; g < 32; ++g) t += red[g][tid];
    hp[tid] = fmaxf(t, 0.f);
  }
  __syncthreads();
  if (tid < 8) {
    float t = bhead[tid];
    for (int k = 0; k < 32; ++k) t += Whead[tid * 32 + k] * hp[k];
    logits[tid] = t;
  }
  __syncthreads();
  if (tid == 0) {
    float mx = logits[0];
    for (int j = 1; j < 8; ++j) mx = fmaxf(mx, logits[j]);
    float e[8], sum = 0.f;
    for (int j = 0; j < 8; ++j) {
      e[j] = __expf(logits[j] - mx);
      sum += e[j];
    }
    for (int j = 0; j < 8; ++j) out[j] = e[j] / sum;
    out[8] = v[pos[0] * HW + pos[1]];
  }
}

extern "C" void kernel_launch(void* const* d_in, const int* in_sizes, int n_in,
                              void* d_out, int out_size, void* d_ws,
                              size_t ws_size, hipStream_t stream) {
  const float* x = (const float*)d_in[0];
  const int* pos = (const int*)d_in[1];
  const float* W1 = (const float*)d_in[2];
  const float* b1 = (const float*)d_in[3];
  const float* W2 = (const float*)d_in[4];
  const float* b2 = (const float*)d_in[5];
  const float* Wro = (const float*)d_in[6];
  const float* bro = (const float*)d_in[7];
  const float* Wri = (const float*)d_in[8];
  const float* bri = (const float*)d_in[9];
  const float* Wp = (const float*)d_in[10];
  const float* bp = (const float*)d_in[11];
  const float* Wpol = (const float*)d_in[12];
  const float* bpol = (const float*)d_in[13];
  const float* Whead = (const float*)d_in[14];
  const float* bhead = (const float*)d_in[15];
  float* ws = (float*)d_ws;
  float* out = (float*)d_out;

  float* part1 = ws + WS_PART1;
  float* partPx = ws + WS_PARTPX;
  float* partPv = ws + WS_PARTPV;
  float* h2 = ws + WS_H2;
  float* pbuf = ws + WS_P;
  float* rdbuf = ws + WS_RD;
  float* vbuf = ws + WS_V;

  // K1: W1@x partials (flat sweep of W1)
  mv_w1<<<1536, 256, 0, stream>>>((const float4*)W1, (const float4*)x, part1);
  // K1b: WpolX partials (flat sweep of the WHOLE Wpol allocation)
  mv_polx<<<2048, 256, 0, stream>>>((const float4*)Wpol, (const float4*)x,
                                    partPx);
  // K2: h1 -> h2
  finish_h<<<1, 1024, 0, stream>>>(part1, b1, W2, b2, h2);
  // K3: p, rd
  rop_kernel<<<1024, 256, 0, stream>>>((const float4*)Wro, bro,
                                       (const float4*)Wri, bri,
                                       (const float4*)Wp, bp, h2, pbuf, rdbuf);
  // K4: 10 value-iteration steps, one launch
  valiter_kernel<<<1024, 256, 0, stream>>>(pbuf, rdbuf, vbuf);
  // K5: WpolV partials
  mv_polv<<<512, 256, 0, stream>>>((const float4*)Wpol, (const float4*)vbuf,
                                   partPv);
  // K6: heads + softmax + state value
  finish_pol<<<1, 1024, 0, stream>>>(partPx, partPv, bpol, Whead, bhead, vbuf,
                                     pos, out);
}

// Round 14
// 118.262 us; speedup vs baseline: 1.0971x; 1.0804x over previous
//
#include <hip/hip_runtime.h>

#define HW 512
#define NSTATE (HW * HW)   // 262144
#define NC4_X 196608       // x as float4 (3*H*W/4)
#define NC4_POLROW 262144  // Wpol row stride in float4 (4 MiB)
#define NC4_V 65536        // v as float4

#define CH4 1024   // float4 per wave-chunk (16 KB)
#define NCH_X 192  // chunks per W1 row
#define SPAN_ROP 1024

// ws layout (float offsets)
#define WS_PART1 0      // 192*32 = 6144
#define WS_PARTP 6144   // 256*32 = 8192 (rows 0..63 = v-part, 64..255 = x-part)
#define WS_H2 14336     // 64
#define WS_P 14400      // 262144
#define WS_RD (WS_P + NSTATE)
#define WS_V (WS_RD + NSTATE)

#define SGB __builtin_amdgcn_sched_group_barrier

__device__ __forceinline__ float wred(float a) {
  a += __shfl_xor(a, 32);
  a += __shfl_xor(a, 16);
  a += __shfl_xor(a, 8);
  a += __shfl_xor(a, 4);
  a += __shfl_xor(a, 2);
  a += __shfl_xor(a, 1);
  return a;
}

// One wave: dot of a contiguous 16 KB W span with the matching operand span,
// both straight from global as 16-load bursts (one base + immediate offsets).
__device__ __forceinline__ float span_dot(const float4* __restrict__ wp,
                                          const float4* __restrict__ xp) {
  float acc = 0.f;
#pragma unroll
  for (int bt = 0; bt < 2; ++bt) {
    float4 w[8], xv[8];
#pragma unroll
    for (int j = 0; j < 8; ++j) w[j] = wp[bt * 512 + j * 64];
#pragma unroll
    for (int j = 0; j < 8; ++j) xv[j] = xp[bt * 512 + j * 64];
    SGB(0x020, 16, 0);  // the 16-load cluster
#pragma unroll
    for (int j = 0; j < 8; ++j)
      acc += w[j].x * xv[j].x + w[j].y * xv[j].y + w[j].z * xv[j].z +
             w[j].w * xv[j].w;
  }
  return acc;
}

// ---------------------------------------------------------------------------
// K1: W1@x partials, flat-linear over the W1 allocation (budget-confirmed
// ~14-16 µs via R10's measured ropx). 1536 blocks.
// ---------------------------------------------------------------------------
__global__ __launch_bounds__(256) void mv_w1(const float4* __restrict__ W1,
                                             const float4* __restrict__ x,
                                             float* __restrict__ part1) {
  int b = blockIdx.x;  // [0,1536)
  int row = b / 48, cb = b - row * 48;
  int tid = threadIdx.x, wave = tid >> 6, lane = tid & 63;
  int ch = cb * 4 + wave;  // chunk-in-row 0..191
  const float4* __restrict__ wp =
      W1 + (size_t)row * NC4_X + (size_t)ch * CH4 + lane;
  const float4* __restrict__ xp = x + (size_t)ch * CH4 + lane;
  float acc = span_dot(wp, xp);
  acc = wred(acc);
  if (lane == 0) part1[ch * 32 + row] = acc;
}

// ---------------------------------------------------------------------------
// finish_h: reduce part1[192][32] -> h1 = relu(W1@x+b1); h2 = relu(W2@h1+b2).
// ---------------------------------------------------------------------------
__global__ __launch_bounds__(1024) void finish_h(
    const float* __restrict__ partials, const float* __restrict__ b1,
    const float* __restrict__ W2, const float* __restrict__ b2,
    float* __restrict__ h2out) {
  __shared__ float red[32][32];
  __shared__ float h1[32];
  int tid = threadIdx.x;
  int row = tid & 31, grp = tid >> 5;
  float s = 0.f;
  for (int b = grp; b < NCH_X; b += 32) s += partials[b * 32 + row];
  red[grp][row] = s;
  __syncthreads();
  if (tid < 32) {
    float t = b1[tid];
    for (int g = 0; g < 32; ++g) t += red[g][tid];
    h1[tid] = fmaxf(t, 0.f);
  }
  __syncthreads();
  if (tid < 64) {
    float t = b2[tid];
    for (int k = 0; k < 32; ++k) t += W2[tid * 32 + k] * h1[k];
    h2out[tid] = fmaxf(t, 0.f);
  }
}

// ---------------------------------------------------------------------------
// rop: p = sig(Wp@h2+bp), rd = sig(Wri@h2+bri) - sig(Wro@h2+bro).
// R5's standalone measured-fast form, unchanged. 1024 blocks.
// ---------------------------------------------------------------------------
__global__ __launch_bounds__(256) void rop_kernel(
    const float4* __restrict__ Wro4, const float* __restrict__ bro,
    const float4* __restrict__ Wri4, const float* __restrict__ bri,
    const float4* __restrict__ Wp4, const float* __restrict__ bp,
    const float* __restrict__ h2, float* __restrict__ p_out,
    float* __restrict__ rd_out) {
  __shared__ float dots[4][3][64];
  int tid = threadIdx.x;
  int wave = tid >> 6, lane = tid & 63;
  int grp = lane >> 4;
  float4 h4 = ((const float4*)h2)[lane & 15];
  int span = blockIdx.x * 4 + wave;       // [0,4096)
  size_t base = (size_t)span * SPAN_ROP;  // first float4 of span
  const float4* mats[3] = {Wro4, Wri4, Wp4};
#pragma unroll
  for (int m = 0; m < 3; ++m) {
    const float4* __restrict__ W = mats[m] + base + lane;
#pragma unroll
    for (int batch = 0; batch < 2; ++batch) {
      float4 w[8];
#pragma unroll
      for (int j = 0; j < 8; ++j) w[j] = W[(batch * 8 + j) * 64];
      SGB(0x020, 8, 0);
      float part[8];
#pragma unroll
      for (int j = 0; j < 8; ++j)
        part[j] = w[j].x * h4.x + w[j].y * h4.y + w[j].z * h4.z + w[j].w * h4.w;
#pragma unroll
      for (int j = 0; j < 8; ++j) {
        part[j] += __shfl_xor(part[j], 8);
        part[j] += __shfl_xor(part[j], 4);
        part[j] += __shfl_xor(part[j], 2);
        part[j] += __shfl_xor(part[j], 1);
      }
      if ((lane & 15) == 0) {
#pragma unroll
        for (int j = 0; j < 8; ++j)
          dots[wave][m][(batch * 8 + j) * 4 + grp] = part[j];
      }
    }
  }
  __syncthreads();
  int o = blockIdx.x * 256 + tid;
  float dro = dots[tid >> 6][0][tid & 63] + bro[o];
  float dri = dots[tid >> 6][1][tid & 63] + bri[o];
  float dp = dots[tid >> 6][2][tid & 63] + bp[o];
  float sro = 1.f / (1.f + __expf(-dro));
  float sri = 1.f / (1.f + __expf(-dri));
  float pv = 1.f / (1.f + __expf(-dp));
  p_out[o] = pv;
  rd_out[o] = sri - sro;
}

// ---------------------------------------------------------------------------
// Value iteration, ONE launch, 1024 blocks. 16x16 tile + halo 10 in LDS,
// 10 local iterations; zero-padding semantics preserved.
// ---------------------------------------------------------------------------
#define TILE 16
#define HALO 10
#define LR 36  // TILE + 2*HALO
__global__ __launch_bounds__(256) void valiter_kernel(
    const float* __restrict__ p, const float* __restrict__ rd,
    float* __restrict__ vout) {
  __shared__ float u[LR + 2][LR + 3];
  __shared__ float pp[LR][LR + 1];
  __shared__ float rr[LR][LR + 1];
  __shared__ float vv[LR][LR + 1];
  int tid = threadIdx.x;
  int ti = blockIdx.x >> 5, tj = blockIdx.x & 31;
  int gi0 = ti * TILE - HALO, gj0 = tj * TILE - HALO;
  for (int idx = tid; idx < (LR + 2) * (LR + 3); idx += 256)
    ((float*)u)[idx] = 0.f;
  for (int idx = tid; idx < LR * LR; idx += 256) {
    int i = idx / LR, j = idx % LR;
    int gi = gi0 + i, gj = gj0 + j;
    bool ok = (gi >= 0) & (gi < HW) & (gj >= 0) & (gj < HW);
    pp[i][j] = ok ? p[gi * HW + gj] : 0.f;
    rr[i][j] = ok ? rd[gi * HW + gj] : 0.f;
    vv[i][j] = 0.f;
  }
  __syncthreads();
  for (int k = 0; k < 10; ++k) {
#pragma unroll
    for (int idx = tid; idx < LR * LR; idx += 256) {
      int i = idx / LR, j = idx % LR;
      u[i + 1][j + 1] = vv[i][j] * pp[i][j] + rr[i][j];
    }
    __syncthreads();
#pragma unroll
    for (int idx = tid; idx < LR * LR; idx += 256) {
      int i = idx / LR, j = idx % LR;
      float m = u[i][j];
      m = fmaxf(m, u[i][j + 1]);
      m = fmaxf(m, u[i][j + 2]);
      m = fmaxf(m, u[i + 1][j]);
      m = fmaxf(m, u[i + 1][j + 2]);
      m = fmaxf(m, u[i + 2][j]);
      m = fmaxf(m, u[i + 2][j + 1]);
      m = fmaxf(m, u[i + 2][j + 2]);
      vv[i][j] = m;
    }
    __syncthreads();
  }
  if (tid < TILE * TILE) {
    int a = tid >> 4, b = tid & 15;
    vout[(ti * TILE + a) * HW + tj * TILE + b] = vv[HALO + a][HALO + b];
  }
}

// ---------------------------------------------------------------------------
// K5: ALL of Wpol in ONE flat sweep, AFTER valiter (v available): flat chunk
// f=(row=f>>8, rc=f&255); rc<64 dots v chunk rc, rc>=64 dots x chunk rc-64.
// Merges R13's polx+polv, removes dummy reads, and tests whether the Wpol-x
// bytes' 10-round ~2.1 TB/s curse is pipeline-POSITION dependent (polv's
// late slot always looked fast) or buffer-intrinsic. 2048 blocks, 128 MiB.
// ---------------------------------------------------------------------------
__global__ __launch_bounds__(256) void mv_pol(const float4* __restrict__ Wpol,
                                              const float4* __restrict__ x,
                                              const float4* __restrict__ v,
                                              float* __restrict__ partP) {
  int b = blockIdx.x;  // [0,2048)
  int tid = threadIdx.x, wave = tid >> 6, lane = tid & 63;
  int f = b * 4 + wave;  // flat chunk [0,8192)
  int row = f >> 8, rc = f & 255;
  const float4* __restrict__ wp = Wpol + (size_t)f * CH4 + lane;  // flat
  const float4* __restrict__ xp =
      (rc < 64) ? (v + (size_t)rc * CH4 + lane)
                : (x + (size_t)(rc - 64) * CH4 + lane);
  float acc = span_dot(wp, xp);
  acc = wred(acc);
  if (lane == 0) partP[rc * 32 + row] = acc;
}

// ---------------------------------------------------------------------------
// finish_pol: hp = relu(bpol + sum over ALL 256 partial rows of partP);
// logits = Whead@hp + bhead; softmax; out[8] = v[pos].
// ---------------------------------------------------------------------------
__global__ __launch_bounds__(1024) void finish_pol(
    const float* __restrict__ partP, const float* __restrict__ bpol,
    const float* __restrict__ Whead, const float* __restrict__ bhead,
    const float* __restrict__ v, const int* __restrict__ pos,
    float* __restrict__ out) {
  __shared__ float red[32][32];
  __shared__ float hp[32];
  __shared__ float logits[8];
  int tid = threadIdx.x;
  int row = tid & 31, grp = tid >> 5;
  float s = 0.f;
  for (int b = grp; b < 256; b += 32) s += partP[b * 32 + row];
  red[grp][row] = s;
  __syncthreads();
  if (tid < 32) {
    float t = bpol[tid];
    for (int g = 0; g < 32; ++g) t += red[g][tid];
    hp[tid] = fmaxf(t, 0.f);
  }
  __syncthreads();
  if (tid < 8) {
    float t = bhead[tid];
    for (int k = 0; k < 32; ++k) t += Whead[tid * 32 + k] * hp[k];
    logits[tid] = t;
  }
  __syncthreads();
  if (tid == 0) {
    float mx = logits[0];
    for (int j = 1; j < 8; ++j) mx = fmaxf(mx, logits[j]);
    float e[8], sum = 0.f;
    for (int j = 0; j < 8; ++j) {
      e[j] = __expf(logits[j] - mx);
      sum += e[j];
    }
    for (int j = 0; j < 8; ++j) out[j] = e[j] / sum;
    out[8] = v[pos[0] * HW + pos[1]];
  }
}

extern "C" void kernel_launch(void* const* d_in, const int* in_sizes, int n_in,
                              void* d_out, int out_size, void* d_ws,
                              size_t ws_size, hipStream_t stream) {
  const float* x = (const float*)d_in[0];
  const int* pos = (const int*)d_in[1];
  const float* W1 = (const float*)d_in[2];
  const float* b1 = (const float*)d_in[3];
  const float* W2 = (const float*)d_in[4];
  const float* b2 = (const float*)d_in[5];
  const float* Wro = (const float*)d_in[6];
  const float* bro = (const float*)d_in[7];
  const float* Wri = (const float*)d_in[8];
  const float* bri = (const float*)d_in[9];
  const float* Wp = (const float*)d_in[10];
  const float* bp = (const float*)d_in[11];
  const float* Wpol = (const float*)d_in[12];
  const float* bpol = (const float*)d_in[13];
  const float* Whead = (const float*)d_in[14];
  const float* bhead = (const float*)d_in[15];
  float* ws = (float*)d_ws;
  float* out = (float*)d_out;

  float* part1 = ws + WS_PART1;
  float* partP = ws + WS_PARTP;
  float* h2 = ws + WS_H2;
  float* pbuf = ws + WS_P;
  float* rdbuf = ws + WS_RD;
  float* vbuf = ws + WS_V;

  // K1: W1@x partials (flat sweep)
  mv_w1<<<1536, 256, 0, stream>>>((const float4*)W1, (const float4*)x, part1);
  // K2: h1 -> h2
  finish_h<<<1, 1024, 0, stream>>>(part1, b1, W2, b2, h2);
  // K3: p, rd
  rop_kernel<<<1024, 256, 0, stream>>>((const float4*)Wro, bro,
                                       (const float4*)Wri, bri,
                                       (const float4*)Wp, bp, h2, pbuf, rdbuf);
  // K4: 10 value-iteration steps, one launch
  valiter_kernel<<<1024, 256, 0, stream>>>(pbuf, rdbuf, vbuf);
  // K5: ALL Wpol partials in one flat sweep (v + x columns)
  mv_pol<<<2048, 256, 0, stream>>>((const float4*)Wpol, (const float4*)x,
                                   (const float4*)vbuf, partP);
  // K6: heads + softmax + state value
  finish_pol<<<1, 1024, 0, stream>>>(partP, bpol, Whead, bhead, vbuf, pos,
                                     out);
}